// Round 11
// baseline (225.053 us; speedup 1.0000x reference)
//
#include <hip/hip_runtime.h>
#include <math.h>
#include <string.h>

#define NBATCH 16

typedef __attribute__((ext_vector_type(8))) short short8;
typedef __attribute__((ext_vector_type(4))) float floatx4;
#define MFMA16(a, b, c) __builtin_amdgcn_mfma_f32_16x16x32_bf16(a, b, c, 0, 0, 0)

// forced-resident global load: asm volatile cannot be sunk by ANY compiler
// pass; output regs stay live from issue to use. Waitcnt is MANUAL.
#define GLOAD(dst, ptr, offlit)                                   \
  asm volatile("global_load_dwordx4 %0, %1, off offset:" offlit   \
               : "=&v"(dst)                                       \
               : "v"(ptr)                                         \
               : "memory")

// hardware RNE bf16 conversion (1 VALU op per pair vs ~10 for manual RNE)
__device__ __forceinline__ unsigned int cvtpk(float a, float b) {
  unsigned int r;
  asm("v_cvt_pk_bf16_f32 %0, %1, %2" : "=v"(r) : "v"(a), "v"(b));
  return r;
}
__device__ __forceinline__ unsigned short f2bf(float f) {
  return (unsigned short)(cvtpk(f, 0.f) & 0xffffu);
}
__device__ __forceinline__ unsigned int packbf2(float a, float b) {
  return cvtpk(a, b);
}
__device__ __forceinline__ float bflo(unsigned int u) {
  return __uint_as_float(u << 16);
}
__device__ __forceinline__ float bfhi(unsigned int u) {
  return __uint_as_float(u & 0xffff0000u);
}
__device__ __forceinline__ float fast_tanh(float x) {
  float e = __expf(2.f * x);
  return 1.f - 2.f / (e + 1.f);
}

// ---------------------------------------------------------------------------
// prep_all: merged xb_prep (blockIdx.x < 64) + prep_weights (blockIdx.x >= 64)
// ---------------------------------------------------------------------------
__global__ __launch_bounds__(256) void prep_all(
    const float* __restrict__ x, unsigned short* __restrict__ xb,
    const float* __restrict__ w1, const float* __restrict__ w2,
    const float* __restrict__ coef, unsigned short* __restrict__ w1swz,
    unsigned short* __restrict__ w2swz, unsigned short* __restrict__ coefswz) {
  __shared__ float tile[64][65];
  const int t = threadIdx.x;
  if (blockIdx.x < 64) {
    const int y = blockIdx.x, n = blockIdx.y;
    const float* xn = x + (size_t)n * 64 * 4096 + y * 64;
#pragma unroll
    for (int it = 0; it < 16; ++it) {
      int idx = it * 256 + t;
      int c = idx >> 6, xx = idx & 63;
      tile[c][xx] = xn[c * 4096 + xx];
    }
    __syncthreads();
    const int xx = t >> 2, cq = t & 3;
    unsigned short* dst = xb + ((size_t)n * 4096 + y * 64 + xx) * 64;
#pragma unroll
    for (int jj = 0; jj < 2; ++jj) {
      int ch0 = cq * 16 + jj * 8;
      unsigned int p[4];
#pragma unroll
      for (int e = 0; e < 4; ++e)
        p[e] = packbf2(tile[ch0 + e * 2][xx], tile[ch0 + e * 2 + 1][xx]);
      *(uint4*)&dst[ch0] = make_uint4(p[0], p[1], p[2], p[3]);
    }
    return;
  }
  // weights part: reproduce old 512-block x 256-thread index space
  int i = ((blockIdx.x - 64) * NBATCH + blockIdx.y) * 256 + t;
  if (i < 131072) {
    int j = i & 7, f = i >> 3;
    int lane = f & 63;
    int u = (f >> 6) & 3;
    int wj = (f >> 8) & 1;
    int kc = (f >> 9) & 1;
    int rd = f >> 10;
    int lm = lane & 15, lq = lane >> 4;
    int oc = wj * 64 + u * 16 + lm;
    int k = rd * 64 + kc * 32 + lq * 8 + j;
    coefswz[i] = f2bf(coef[oc * 1024 + k]);
  }
  if (i < 36864) {
    int j = i & 7, f = i >> 3;
    int lane = f & 63;
    int u = (f >> 6) & 1;
    int wn = (f >> 7) & 1;
    int kc = (f >> 8) & 1;
    int off = f >> 9;
    int lm = lane & 15, lq = lane >> 4;
    int oc = wn * 32 + u * 16 + lm;
    int ic = kc * 32 + lq * 8 + j;
    w1swz[i] = f2bf(w1[(oc * 64 + ic) * 9 + off]);
  }
  if (i < 55296) {
    int j = i & 7, f = i >> 3;
    int lane = f & 63;
    int rem = f >> 6;
    int u = rem % 3;
    int rem2 = rem / 3;
    int wn = rem2 & 1;
    int kc = (rem2 >> 1) & 1;
    int off = rem2 >> 2;
    int lm = lane & 15, lq = lane >> 4;
    int oc = wn * 48 + u * 16 + lm;
    int ic = kc * 32 + lq * 8 + j;
    w2swz[i] = f2bf(w2[(oc * 64 + ic) * 9 + off]);
  }
}

// ---------------------------------------------------------------------------
// mega v2: LDS LIVENESS UNION -> 3 blocks/CU.
// R10 post-mortem: merge worked (WRITE=out exactly; mega 84us < pair 97us)
// but stayed 2 blocks/CU (LDS 70KB) and latency-bound (Mfma+VALU=61%).
// Buffers are never all live: xls (conv halo, 20.7KB) dies after conv1;
// xs+As (22.6KB) not needed until after conv2 (the two x-halos are
// TRANSPOSED regions -- reference's transpose(1,-1) -- so data can't be
// shared, but storage can). Union:
//   [0      .. 22592): xls (conv phases)  ->  xs (14400) + As (8192)
//   [22592  .. 36992): hls
//   [36992  .. 49280): lbc
// = 49,280 B -> 3 blocks/CU (3x49280=147.8KB <= 160KB). xs is re-staged
// after conv2 (~115KB L2-hot reads/block, ~1us total).
// Phase order: stage xls / sync / conv1->hls / sync / conv2->lbc / sync /
// [stage xs over dead xls || atoms from lbc] / sync / adconv main loop.
// __launch_bounds__(256,3): reg cap 170 >> 96 used -- no forced spill.
// Gates: LDS ~49.4KB, Occupancy ~28%, WRITE 32768KB, absmax 0.09375.
// Predict mega 84 -> 66-74us.
// ---------------------------------------------------------------------------
__global__ __launch_bounds__(256, 3) void mega(
    const unsigned short* __restrict__ xb, const unsigned short* __restrict__ w1swz,
    const unsigned short* __restrict__ w2swz, const float* __restrict__ b1,
    const float* __restrict__ g1, const float* __restrict__ be1,
    const float* __restrict__ m1, const float* __restrict__ v1,
    const float* __restrict__ b2, const float* __restrict__ g2,
    const float* __restrict__ be2, const float* __restrict__ m2,
    const float* __restrict__ v2, const float* __restrict__ bases,
    const unsigned short* __restrict__ coefswz, float* __restrict__ out) {
  __shared__ alignas(16) unsigned char smem[49280];
  unsigned short* xls = (unsigned short*)smem;             // [0, 20736)
  unsigned short* hls = (unsigned short*)(smem + 22592);   // [22592, 36992)
  unsigned short* lbc = (unsigned short*)(smem + 36992);   // [36992, 49280)
  unsigned short* xs = (unsigned short*)smem;              // [0, 14400) late
  unsigned short* As = (unsigned short*)(smem + 14400);    // [14400, 22592)

  const int t = threadIdx.x;
  const int tile = blockIdx.x, n = blockIdx.y;
  const int x0 = (tile & 7) * 8, y0 = (tile >> 3) * 8;
  const int q0 = y0, p0 = x0;  // adconv-part coordinates (verified mapping)

  const unsigned short* xbn = xb + (size_t)n * 4096 * 64;

  // ---- stage xls (conv halo, (y,x) orientation) ----
#pragma unroll
  for (int it = 0; it < 5; ++it) {
    int idx = it * 256 + t;  // 1152 total
    if (idx < 1152) {
      int pos = idx >> 3, u4 = idx & 7;
      int xr = pos / 12, xc = pos - xr * 12;
      int gy = y0 - 2 + xr, gx = x0 - 2 + xc;
      uint4 v = {0u, 0u, 0u, 0u};
      if ((unsigned)gy < 64u && (unsigned)gx < 64u)
        v = *(const uint4*)&xbn[((size_t)gy * 64 + gx) * 64 + u4 * 8];
      *(uint4*)&xls[pos * 72 + u4 * 8] = v;
    }
  }
  __syncthreads();

  const int lane = t & 63, w = t >> 6;
  const int wm = w & 1, wn = w >> 1;
  const int lm = lane & 15, lq = lane >> 4;

  // ---- phase 1: h = tanh(bn1(conv1(x))), M=128 (100 used), N=64, K=576 ----
  {
    int abase[4];
#pragma unroll
    for (int i = 0; i < 4; ++i) {
      int px = (wm + 2 * i) * 16 + lm;
      if (px > 99) px = 99;
      int hr = px / 10, hc = px - hr * 10;
      abase[i] = (hr * 12 + hc) * 72 + lq * 8;
    }
    floatx4 acc[4][2];
#pragma unroll
    for (int i = 0; i < 4; ++i)
#pragma unroll
      for (int u = 0; u < 2; ++u) acc[i][u] = floatx4{0.f, 0.f, 0.f, 0.f};

#pragma unroll
    for (int step = 0; step < 18; ++step) {
      const int off = step >> 1, kc = step & 1;
      const int di = off / 3, dj = off % 3;
      short8 b[2];
#pragma unroll
      for (int u = 0; u < 2; ++u)
        b[u] = *(const short8*)&w1swz[(off * 512 + kc * 256 + wn * 128 +
                                       u * 64 + lane) * 8];
#pragma unroll
      for (int i = 0; i < 4; ++i) {
        short8 a =
            *(const short8*)&xls[abase[i] + (di * 12 + dj) * 72 + kc * 32];
        acc[i][0] = MFMA16(a, b[0], acc[i][0]);
        acc[i][1] = MFMA16(a, b[1], acc[i][1]);
      }
    }
    float sc[2], sh[2];
#pragma unroll
    for (int u = 0; u < 2; ++u) {
      int oc = wn * 32 + u * 16 + lm;
      sc[u] = g1[oc] * rsqrtf(v1[oc] + 1e-5f);
      sh[u] = (b1[oc] - m1[oc]) * sc[u] + be1[oc];
    }
#pragma unroll
    for (int i = 0; i < 4; ++i) {
      int px0 = (wm + 2 * i) * 16 + lq * 4;
#pragma unroll
      for (int u = 0; u < 2; ++u) {
        int oc = wn * 32 + u * 16 + lm;
#pragma unroll
        for (int r = 0; r < 4; ++r) {
          int px = px0 + r;
          if (px < 100) {
            int hr = px / 10, hc = px - hr * 10;
            int gy = y0 - 1 + hr, gx = x0 - 1 + hc;
            bool valid = ((unsigned)gy < 64u) && ((unsigned)gx < 64u);
            float val = valid ? fast_tanh(acc[i][u][r] * sc[u] + sh[u]) : 0.f;
            hls[px * 72 + oc] = f2bf(val);
          }
        }
      }
    }
  }
  __syncthreads();

  // ---- phase 2: bc = tanh(bn2(conv2(h))) -> lbc (LDS), M=64, N=96 ----
  {
    int hbase[2];
#pragma unroll
    for (int s = 0; s < 2; ++s) {
      int opx = (wm + 2 * s) * 16 + lm;
      int yl = opx >> 3, xl = opx & 7;
      hbase[s] = (yl * 10 + xl) * 72 + lq * 8;
    }
    floatx4 acc2[2][3];
#pragma unroll
    for (int s = 0; s < 2; ++s)
#pragma unroll
      for (int u = 0; u < 3; ++u) acc2[s][u] = floatx4{0.f, 0.f, 0.f, 0.f};

#pragma unroll
    for (int step = 0; step < 18; ++step) {
      const int off = step >> 1, kc = step & 1;
      const int di = off / 3, dj = off % 3;
      short8 b[3];
#pragma unroll
      for (int u = 0; u < 3; ++u)
        b[u] = *(const short8*)&w2swz[(off * 768 + kc * 384 + wn * 192 +
                                       u * 64 + lane) * 8];
#pragma unroll
      for (int s = 0; s < 2; ++s) {
        short8 a =
            *(const short8*)&hls[hbase[s] + (di * 10 + dj) * 72 + kc * 32];
        acc2[s][0] = MFMA16(a, b[0], acc2[s][0]);
        acc2[s][1] = MFMA16(a, b[1], acc2[s][1]);
        acc2[s][2] = MFMA16(a, b[2], acc2[s][2]);
      }
    }
    float sc[3], sh[3];
#pragma unroll
    for (int u = 0; u < 3; ++u) {
      int oc = wn * 48 + u * 16 + lm;
      sc[u] = g2[oc] * rsqrtf(v2[oc] + 1e-5f);
      sh[u] = (b2[oc] - m2[oc]) * sc[u] + be2[oc];
    }
#pragma unroll
    for (int s = 0; s < 2; ++s) {
      int opx0 = (wm + 2 * s) * 16 + lq * 4;
#pragma unroll
      for (int u = 0; u < 3; ++u) {
        int oc = wn * 48 + u * 16 + lm;
#pragma unroll
        for (int r = 0; r < 4; ++r) {
          int opx = opx0 + r;  // local pixel, == adconv's px_b numbering
          lbc[opx * 96 + oc] = f2bf(fast_tanh(acc2[s][u][r] * sc[u] + sh[u]));
        }
      }
    }
  }
  __syncthreads();  // conv done: xls dead, lbc live

  // ================== adconv part (bc -> lbc, xs over dead xls) ==========
  float bs[54];
#pragma unroll
  for (int i = 0; i < 54; ++i) bs[i] = bases[i];

  // ---- stage xs (adconv halo, (p,q) orientation) over dead xls, while
  //      computing atoms from lbc (disjoint LDS regions, no race) ----
#pragma unroll
  for (int it = 0; it < 4; ++it) {
    int idx = it * 256 + t;  // 800 total
    if (idx < 800) {
      int pos = idx >> 3, u4 = idx & 7;
      int row = pos / 10, col = pos - row * 10;
      int gp = p0 - 1 + row, gq = q0 - 1 + col;
      uint4 v = {0u, 0u, 0u, 0u};
      if ((unsigned)gp < 64u && (unsigned)gq < 64u)
        v = *(const uint4*)&xbn[((size_t)gp * 64 + gq) * 64 + u4 * 8];
      *(uint4*)&xs[pos * 72 + u4 * 8] = v;
    }
  }

  // builder role: 4 threads/px, wave-aligned (wave w builds px w*16..+15)
  const int pxl_b = lane >> 2, fh4 = lane & 3;  // local px, f-quarter
  const int px_b = w * 16 + pxl_b;
  const int qx_b = px_b >> 3, py_b = px_b & 7;

  // atoms[k][j] for f = fh4*4 + j (j<4), f32 (36 VGPRs); bc read from LDS
  float atf[9][4];
  {
    const unsigned short* bp = &lbc[px_b * 96 + fh4 * 24];
    float bcv[24];
#pragma unroll
    for (int m = 0; m < 3; ++m) {
      uint4 v = *(const uint4*)(bp + m * 8);
      unsigned int uu[4] = {v.x, v.y, v.z, v.w};
#pragma unroll
      for (int e = 0; e < 4; ++e) {
        bcv[m * 8 + e * 2] = bflo(uu[e]);
        bcv[m * 8 + e * 2 + 1] = bfhi(uu[e]);
      }
    }
#pragma unroll
    for (int j = 0; j < 4; ++j)
#pragma unroll
      for (int k = 0; k < 9; ++k) {
        float s0 = 0.f;
#pragma unroll
        for (int tt = 0; tt < 6; ++tt)
          s0 = fmaf(bcv[j * 6 + tt], bs[tt * 9 + k], s0);
        atf[k][j] = s0;
      }
  }
  __syncthreads();  // xs staged

  int pa[9];
#pragma unroll
  for (int i = 0; i < 3; ++i)
#pragma unroll
    for (int j = 0; j < 3; ++j)
      pa[i * 3 + j] = ((py_b + i) * 10 + qx_b + j) * 72;

  floatx4 acc[2][4];  // [wj][u]: full N=128 per wave
#pragma unroll
  for (int wj = 0; wj < 2; ++wj)
#pragma unroll
    for (int u = 0; u < 4; ++u) acc[wj][u] = floatx4{0.f, 0.f, 0.f, 0.f};

  unsigned short* Asw = As + w * 1024;  // wave-private single buffer

  uint2 qv[9];
  auto qload = [&](int rd) {
    const int coff = rd * 4;
#pragma unroll
    for (int p = 0; p < 9; ++p) qv[p] = *(const uint2*)&xs[pa[p] + coff];
  };
  auto build = [&]() {
    float a[4][4];
    {  // p = 0: mul (no zero-init pass)
      float c0 = bflo(qv[0].x), c1 = bfhi(qv[0].x);
      float c2 = bflo(qv[0].y), c3 = bfhi(qv[0].y);
#pragma unroll
      for (int j = 0; j < 4; ++j) {
        float av = atf[0][j];
        a[0][j] = c0 * av;
        a[1][j] = c1 * av;
        a[2][j] = c2 * av;
        a[3][j] = c3 * av;
      }
    }
#pragma unroll
    for (int p = 1; p < 9; ++p) {
      float c0 = bflo(qv[p].x), c1 = bfhi(qv[p].x);
      float c2 = bflo(qv[p].y), c3 = bfhi(qv[p].y);
#pragma unroll
      for (int j = 0; j < 4; ++j) {
        float av = atf[p][j];
        a[0][j] = fmaf(c0, av, a[0][j]);
        a[1][j] = fmaf(c1, av, a[1][j]);
        a[2][j] = fmaf(c2, av, a[2][j]);
        a[3][j] = fmaf(c3, av, a[3][j]);
      }
    }
#pragma unroll
    for (int cc = 0; cc < 4; ++cc) {
      int g = (cc * 4 + fh4) ^ ((pxl_b & 7) << 1);
      uint2 val;
      val.x = cvtpk(a[cc][0], a[cc][1]);
      val.y = cvtpk(a[cc][2], a[cc][3]);
      *(uint2*)&Asw[pxl_b * 64 + g * 4] = val;
    }
  };

  qload(0);
  build();

  for (int rd = 0; rd < 16; ++rd) {
    // 1) issue ALL 16 B-frag loads via asm (un-sinkable).
    short8 Bf[2][2][4];
    {
      const unsigned short* b0 = coefswz + (size_t)rd * 8192 + lane * 8;
      const unsigned short* b1 = b0 + 2048;
      const unsigned short* b2 = b0 + 4096;
      const unsigned short* b3 = b0 + 6144;
      GLOAD(Bf[0][0][0], b0, "0");
      GLOAD(Bf[0][0][1], b0, "1024");
      GLOAD(Bf[0][0][2], b0, "2048");
      GLOAD(Bf[0][0][3], b0, "3072");
      GLOAD(Bf[0][1][0], b1, "0");
      GLOAD(Bf[0][1][1], b1, "1024");
      GLOAD(Bf[0][1][2], b1, "2048");
      GLOAD(Bf[0][1][3], b1, "3072");
      GLOAD(Bf[1][0][0], b2, "0");
      GLOAD(Bf[1][0][1], b2, "1024");
      GLOAD(Bf[1][0][2], b2, "2048");
      GLOAD(Bf[1][0][3], b2, "3072");
      GLOAD(Bf[1][1][0], b3, "0");
      GLOAD(Bf[1][1][1], b3, "1024");
      GLOAD(Bf[1][1][2], b3, "2048");
      GLOAD(Bf[1][1][3], b3, "3072");
    }
    // 2) A frags for rd (per-wave DS in-order -> WAR-safe single buffer)
    short8 Af[2];
#pragma unroll
    for (int kc = 0; kc < 2; ++kc) {
      int u16 = (kc * 4 + lq) ^ (lm & 7);
      Af[kc] = *(const short8*)&Asw[lm * 64 + u16 * 8];
    }
    __builtin_amdgcn_sched_barrier(0);
    // 3) next-chunk build: VALU blanket hiding the B-load latency
    if (rd < 15) {
      qload(rd + 1);
      build();
    }
    // 4) manual wait for the asm loads, fenced (rule #18), then consume.
    asm volatile("s_waitcnt vmcnt(0)" ::: "memory");
    __builtin_amdgcn_sched_barrier(0);
    __builtin_amdgcn_s_setprio(1);
#pragma unroll
    for (int kc = 0; kc < 2; ++kc)
#pragma unroll
      for (int wj = 0; wj < 2; ++wj)
#pragma unroll
        for (int u = 0; u < 4; ++u)
          acc[wj][u] = MFMA16(Af[kc], Bf[kc][wj][u], acc[wj][u]);
    __builtin_amdgcn_s_setprio(0);
  }

  // epilogue: direct float4 stores (C/D reg-run contiguous along p)
  float* outn = out + (size_t)n * 128 * 4096;
#pragma unroll
  for (int wj = 0; wj < 2; ++wj)
#pragma unroll
    for (int u = 0; u < 4; ++u) {
      int oc = wj * 64 + u * 16 + lm;
      int gpx = w * 16 + lq * 4;  // tile-local px of acc run
      int qx = gpx >> 3, py0 = gpx & 7;
      *(float4*)&outn[((size_t)oc * 64 + q0 + qx) * 64 + p0 + py0] =
          make_float4(acc[wj][u][0], acc[wj][u][1], acc[wj][u][2],
                      acc[wj][u][3]);
    }
}

// ---------------------------------------------------------------------------
extern "C" void kernel_launch(void* const* d_in, const int* in_sizes, int n_in,
                              void* d_out, int out_size, void* d_ws,
                              size_t ws_size, hipStream_t stream) {
  const float* x = (const float*)d_in[0];
  const float* conv1_w = (const float*)d_in[1];
  const float* conv1_b = (const float*)d_in[2];
  const float* bn1_g = (const float*)d_in[3];
  const float* bn1_b = (const float*)d_in[4];
  const float* bn1_m = (const float*)d_in[5];
  const float* bn1_v = (const float*)d_in[6];
  const float* conv2_w = (const float*)d_in[7];
  const float* conv2_b = (const float*)d_in[8];
  const float* bn2_g = (const float*)d_in[9];
  const float* bn2_b = (const float*)d_in[10];
  const float* bn2_m = (const float*)d_in[11];
  const float* bn2_v = (const float*)d_in[12];
  const float* bases = (const float*)d_in[13];
  const float* coef = (const float*)d_in[14];
  float* out = (float*)d_out;

  char* ws = (char*)d_ws;
  unsigned short* xbuf = (unsigned short*)(ws);             // 8,388,608 B
  unsigned short* w1swz = (unsigned short*)(ws + 20971520); // 73,728 B
  unsigned short* w2swz = (unsigned short*)(ws + 21045248); // 110,592 B
  unsigned short* coefswz = (unsigned short*)(ws + 21155840); // 262,144 B

  prep_all<<<dim3(96, NBATCH), 256, 0, stream>>>(x, xbuf, conv1_w, conv2_w,
                                                 coef, w1swz, w2swz, coefswz);
  mega<<<dim3(64, NBATCH), 256, 0, stream>>>(
      xbuf, w1swz, w2swz, conv1_b, bn1_g, bn1_b, bn1_m, bn1_v, conv2_b, bn2_g,
      bn2_b, bn2_m, bn2_v, bases, coefswz, out);
}

// Round 13
// 168.879 us; speedup vs baseline: 1.3326x; 1.3326x over previous
//
#include <hip/hip_runtime.h>
#include <math.h>
#include <string.h>

#define NBATCH 16

typedef __attribute__((ext_vector_type(8))) short short8;
typedef __attribute__((ext_vector_type(4))) float floatx4;
#define MFMA16(a, b, c) __builtin_amdgcn_mfma_f32_16x16x32_bf16(a, b, c, 0, 0, 0)

// forced-resident global load: asm volatile cannot be sunk by ANY compiler
// pass; output regs stay live from issue to use. Waitcnt is MANUAL.
#define GLOAD(dst, ptr, offlit)                                   \
  asm volatile("global_load_dwordx4 %0, %1, off offset:" offlit   \
               : "=&v"(dst)                                       \
               : "v"(ptr)                                         \
               : "memory")

// hardware RNE bf16 conversion (1 VALU op per pair vs ~10 for manual RNE)
__device__ __forceinline__ unsigned int cvtpk(float a, float b) {
  unsigned int r;
  asm("v_cvt_pk_bf16_f32 %0, %1, %2" : "=v"(r) : "v"(a), "v"(b));
  return r;
}
__device__ __forceinline__ unsigned short f2bf(float f) {
  return (unsigned short)(cvtpk(f, 0.f) & 0xffffu);
}
__device__ __forceinline__ unsigned int packbf2(float a, float b) {
  return cvtpk(a, b);
}
__device__ __forceinline__ float bflo(unsigned int u) {
  return __uint_as_float(u << 16);
}
__device__ __forceinline__ float bfhi(unsigned int u) {
  return __uint_as_float(u & 0xffff0000u);
}
__device__ __forceinline__ float fast_tanh(float x) {
  float e = __expf(2.f * x);
  return 1.f - 2.f / (e + 1.f);
}

// ---------------------------------------------------------------------------
// prep_all: merged xb_prep (blockIdx.x < 64) + prep_weights (blockIdx.x >= 64)
// ---------------------------------------------------------------------------
__global__ __launch_bounds__(256) void prep_all(
    const float* __restrict__ x, unsigned short* __restrict__ xb,
    const float* __restrict__ w1, const float* __restrict__ w2,
    const float* __restrict__ coef, unsigned short* __restrict__ w1swz,
    unsigned short* __restrict__ w2swz, unsigned short* __restrict__ coefswz) {
  __shared__ float tile[64][65];
  const int t = threadIdx.x;
  if (blockIdx.x < 64) {
    const int y = blockIdx.x, n = blockIdx.y;
    const float* xn = x + (size_t)n * 64 * 4096 + y * 64;
#pragma unroll
    for (int it = 0; it < 16; ++it) {
      int idx = it * 256 + t;
      int c = idx >> 6, xx = idx & 63;
      tile[c][xx] = xn[c * 4096 + xx];
    }
    __syncthreads();
    const int xx = t >> 2, cq = t & 3;
    unsigned short* dst = xb + ((size_t)n * 4096 + y * 64 + xx) * 64;
#pragma unroll
    for (int jj = 0; jj < 2; ++jj) {
      int ch0 = cq * 16 + jj * 8;
      unsigned int p[4];
#pragma unroll
      for (int e = 0; e < 4; ++e)
        p[e] = packbf2(tile[ch0 + e * 2][xx], tile[ch0 + e * 2 + 1][xx]);
      *(uint4*)&dst[ch0] = make_uint4(p[0], p[1], p[2], p[3]);
    }
    return;
  }
  // weights part: reproduce old 512-block x 256-thread index space
  int i = ((blockIdx.x - 64) * NBATCH + blockIdx.y) * 256 + t;
  if (i < 131072) {
    int j = i & 7, f = i >> 3;
    int lane = f & 63;
    int u = (f >> 6) & 3;
    int wj = (f >> 8) & 1;
    int kc = (f >> 9) & 1;
    int rd = f >> 10;
    int lm = lane & 15, lq = lane >> 4;
    int oc = wj * 64 + u * 16 + lm;
    int k = rd * 64 + kc * 32 + lq * 8 + j;
    coefswz[i] = f2bf(coef[oc * 1024 + k]);
  }
  if (i < 36864) {
    int j = i & 7, f = i >> 3;
    int lane = f & 63;
    int u = (f >> 6) & 1;
    int wn = (f >> 7) & 1;
    int kc = (f >> 8) & 1;
    int off = f >> 9;
    int lm = lane & 15, lq = lane >> 4;
    int oc = wn * 32 + u * 16 + lm;
    int ic = kc * 32 + lq * 8 + j;
    w1swz[i] = f2bf(w1[(oc * 64 + ic) * 9 + off]);
  }
  if (i < 55296) {
    int j = i & 7, f = i >> 3;
    int lane = f & 63;
    int rem = f >> 6;
    int u = rem % 3;
    int rem2 = rem / 3;
    int wn = rem2 & 1;
    int kc = (rem2 >> 1) & 1;
    int off = rem2 >> 2;
    int lm = lane & 15, lq = lane >> 4;
    int oc = wn * 48 + u * 16 + lm;
    int ic = kc * 32 + lq * 8 + j;
    w2swz[i] = f2bf(w2[(oc * 64 + ic) * 9 + off]);
  }
}

// ---------------------------------------------------------------------------
// mega (R10 v1, reverted): fused_conv + adconv_final merged; bc through LDS.
// R12 post-mortem: v_pk_fma_f32 op_sel broadcast computed WRONG products on
// HW (packed-f32 VOP3P op_sel semantics differ from the 16-bit packed ops) ->
// correctness fail. Reverted to the scalar-fmaf build, byte-for-byte R10 v1:
// best measured config (mega 83-85us, WRITE=output exactly, absmax 0.09375).
// Ledger: occupancy is register-bound at 2 blocks/CU ((256,3) spills, 3x
// proven); B-load residency needs asm GLOAD (+5%); VALU packing shelved
// pending asm verification. LDS 70,016B; (256,2).
// ---------------------------------------------------------------------------
__global__ __launch_bounds__(256, 2) void mega(
    const unsigned short* __restrict__ xb, const unsigned short* __restrict__ w1swz,
    const unsigned short* __restrict__ w2swz, const float* __restrict__ b1,
    const float* __restrict__ g1, const float* __restrict__ be1,
    const float* __restrict__ m1, const float* __restrict__ v1,
    const float* __restrict__ b2, const float* __restrict__ g2,
    const float* __restrict__ be2, const float* __restrict__ m2,
    const float* __restrict__ v2, const float* __restrict__ bases,
    const unsigned short* __restrict__ coefswz, float* __restrict__ out) {
  __shared__ unsigned short xls[144 * 72];  // conv1 x halo 12x12      20736 B
  __shared__ unsigned short hls[100 * 72];  // h 10x10                 14400 B
  __shared__ unsigned short lbc[64 * 96];   // bc tile (was global)    12288 B
  __shared__ unsigned short As[4 * 1024];   // per-wave A frags         8192 B
  __shared__ unsigned short xs[100 * 72];   // adconv x halo 10x10     14400 B

  const int t = threadIdx.x;
  const int tile = blockIdx.x, n = blockIdx.y;
  const int x0 = (tile & 7) * 8, y0 = (tile >> 3) * 8;
  const int q0 = y0, p0 = x0;  // adconv-part coordinates (verified mapping)

  const unsigned short* xbn = xb + (size_t)n * 4096 * 64;

  // ---- stage xls (conv halo, (y,x) orientation) ----
#pragma unroll
  for (int it = 0; it < 5; ++it) {
    int idx = it * 256 + t;  // 1152 total
    if (idx < 1152) {
      int pos = idx >> 3, u4 = idx & 7;
      int xr = pos / 12, xc = pos - xr * 12;
      int gy = y0 - 2 + xr, gx = x0 - 2 + xc;
      uint4 v = {0u, 0u, 0u, 0u};
      if ((unsigned)gy < 64u && (unsigned)gx < 64u)
        v = *(const uint4*)&xbn[((size_t)gy * 64 + gx) * 64 + u4 * 8];
      *(uint4*)&xls[pos * 72 + u4 * 8] = v;
    }
  }
  // ---- stage xs (adconv halo, (p,q) orientation) ----
#pragma unroll
  for (int it = 0; it < 4; ++it) {
    int idx = it * 256 + t;  // 800 total
    if (idx < 800) {
      int pos = idx >> 3, u4 = idx & 7;
      int row = pos / 10, col = pos - row * 10;
      int gp = p0 - 1 + row, gq = q0 - 1 + col;
      uint4 v = {0u, 0u, 0u, 0u};
      if ((unsigned)gp < 64u && (unsigned)gq < 64u)
        v = *(const uint4*)&xbn[((size_t)gp * 64 + gq) * 64 + u4 * 8];
      *(uint4*)&xs[pos * 72 + u4 * 8] = v;
    }
  }
  __syncthreads();

  const int lane = t & 63, w = t >> 6;
  const int wm = w & 1, wn = w >> 1;
  const int lm = lane & 15, lq = lane >> 4;

  // ---- phase 1: h = tanh(bn1(conv1(x))), M=128 (100 used), N=64, K=576 ----
  {
    int abase[4];
#pragma unroll
    for (int i = 0; i < 4; ++i) {
      int px = (wm + 2 * i) * 16 + lm;
      if (px > 99) px = 99;
      int hr = px / 10, hc = px - hr * 10;
      abase[i] = (hr * 12 + hc) * 72 + lq * 8;
    }
    floatx4 acc[4][2];
#pragma unroll
    for (int i = 0; i < 4; ++i)
#pragma unroll
      for (int u = 0; u < 2; ++u) acc[i][u] = floatx4{0.f, 0.f, 0.f, 0.f};

#pragma unroll
    for (int step = 0; step < 18; ++step) {
      const int off = step >> 1, kc = step & 1;
      const int di = off / 3, dj = off % 3;
      short8 b[2];
#pragma unroll
      for (int u = 0; u < 2; ++u)
        b[u] = *(const short8*)&w1swz[(off * 512 + kc * 256 + wn * 128 +
                                       u * 64 + lane) * 8];
#pragma unroll
      for (int i = 0; i < 4; ++i) {
        short8 a =
            *(const short8*)&xls[abase[i] + (di * 12 + dj) * 72 + kc * 32];
        acc[i][0] = MFMA16(a, b[0], acc[i][0]);
        acc[i][1] = MFMA16(a, b[1], acc[i][1]);
      }
    }
    float sc[2], sh[2];
#pragma unroll
    for (int u = 0; u < 2; ++u) {
      int oc = wn * 32 + u * 16 + lm;
      sc[u] = g1[oc] * rsqrtf(v1[oc] + 1e-5f);
      sh[u] = (b1[oc] - m1[oc]) * sc[u] + be1[oc];
    }
#pragma unroll
    for (int i = 0; i < 4; ++i) {
      int px0 = (wm + 2 * i) * 16 + lq * 4;
#pragma unroll
      for (int u = 0; u < 2; ++u) {
        int oc = wn * 32 + u * 16 + lm;
#pragma unroll
        for (int r = 0; r < 4; ++r) {
          int px = px0 + r;
          if (px < 100) {
            int hr = px / 10, hc = px - hr * 10;
            int gy = y0 - 1 + hr, gx = x0 - 1 + hc;
            bool valid = ((unsigned)gy < 64u) && ((unsigned)gx < 64u);
            float val = valid ? fast_tanh(acc[i][u][r] * sc[u] + sh[u]) : 0.f;
            hls[px * 72 + oc] = f2bf(val);
          }
        }
      }
    }
  }
  __syncthreads();

  // ---- phase 2: bc = tanh(bn2(conv2(h))) -> lbc (LDS), M=64, N=96 ----
  {
    int hbase[2];
#pragma unroll
    for (int s = 0; s < 2; ++s) {
      int opx = (wm + 2 * s) * 16 + lm;
      int yl = opx >> 3, xl = opx & 7;
      hbase[s] = (yl * 10 + xl) * 72 + lq * 8;
    }
    floatx4 acc2[2][3];
#pragma unroll
    for (int s = 0; s < 2; ++s)
#pragma unroll
      for (int u = 0; u < 3; ++u) acc2[s][u] = floatx4{0.f, 0.f, 0.f, 0.f};

#pragma unroll
    for (int step = 0; step < 18; ++step) {
      const int off = step >> 1, kc = step & 1;
      const int di = off / 3, dj = off % 3;
      short8 b[3];
#pragma unroll
      for (int u = 0; u < 3; ++u)
        b[u] = *(const short8*)&w2swz[(off * 768 + kc * 384 + wn * 192 +
                                       u * 64 + lane) * 8];
#pragma unroll
      for (int s = 0; s < 2; ++s) {
        short8 a =
            *(const short8*)&hls[hbase[s] + (di * 10 + dj) * 72 + kc * 32];
        acc2[s][0] = MFMA16(a, b[0], acc2[s][0]);
        acc2[s][1] = MFMA16(a, b[1], acc2[s][1]);
        acc2[s][2] = MFMA16(a, b[2], acc2[s][2]);
      }
    }
    float sc[3], sh[3];
#pragma unroll
    for (int u = 0; u < 3; ++u) {
      int oc = wn * 48 + u * 16 + lm;
      sc[u] = g2[oc] * rsqrtf(v2[oc] + 1e-5f);
      sh[u] = (b2[oc] - m2[oc]) * sc[u] + be2[oc];
    }
#pragma unroll
    for (int s = 0; s < 2; ++s) {
      int opx0 = (wm + 2 * s) * 16 + lq * 4;
#pragma unroll
      for (int u = 0; u < 3; ++u) {
        int oc = wn * 48 + u * 16 + lm;
#pragma unroll
        for (int r = 0; r < 4; ++r) {
          int opx = opx0 + r;  // local pixel, == adconv's px_b numbering
          lbc[opx * 96 + oc] = f2bf(fast_tanh(acc2[s][u][r] * sc[u] + sh[u]));
        }
      }
    }
  }
  __syncthreads();

  // ================== adconv part (v12 body, bc -> lbc) ==================
  float bs[54];
#pragma unroll
  for (int i = 0; i < 54; ++i) bs[i] = bases[i];

  // builder role: 4 threads/px, wave-aligned (wave w builds px w*16..+15)
  const int pxl_b = lane >> 2, fh4 = lane & 3;  // local px, f-quarter
  const int px_b = w * 16 + pxl_b;
  const int qx_b = px_b >> 3, py_b = px_b & 7;

  // atoms[k][j] for f = fh4*4 + j (j<4), f32 (36 VGPRs); bc read from LDS
  float atf[9][4];
  {
    const unsigned short* bp = &lbc[px_b * 96 + fh4 * 24];
    float bcv[24];
#pragma unroll
    for (int m = 0; m < 3; ++m) {
      uint4 v = *(const uint4*)(bp + m * 8);
      unsigned int uu[4] = {v.x, v.y, v.z, v.w};
#pragma unroll
      for (int e = 0; e < 4; ++e) {
        bcv[m * 8 + e * 2] = bflo(uu[e]);
        bcv[m * 8 + e * 2 + 1] = bfhi(uu[e]);
      }
    }
#pragma unroll
    for (int j = 0; j < 4; ++j)
#pragma unroll
      for (int k = 0; k < 9; ++k) {
        float s0 = 0.f;
#pragma unroll
        for (int tt = 0; tt < 6; ++tt)
          s0 = fmaf(bcv[j * 6 + tt], bs[tt * 9 + k], s0);
        atf[k][j] = s0;
      }
  }

  int pa[9];
#pragma unroll
  for (int i = 0; i < 3; ++i)
#pragma unroll
    for (int j = 0; j < 3; ++j)
      pa[i * 3 + j] = ((py_b + i) * 10 + qx_b + j) * 72;

  floatx4 acc[2][4];  // [wj][u]: full N=128 per wave
#pragma unroll
  for (int wj = 0; wj < 2; ++wj)
#pragma unroll
    for (int u = 0; u < 4; ++u) acc[wj][u] = floatx4{0.f, 0.f, 0.f, 0.f};

  unsigned short* Asw = &As[w * 1024];  // wave-private single buffer

  uint2 qv[9];
  auto qload = [&](int rd) {
    const int coff = rd * 4;
#pragma unroll
    for (int p = 0; p < 9; ++p) qv[p] = *(const uint2*)&xs[pa[p] + coff];
  };
  auto build = [&]() {
    float a[4][4];
    {  // p = 0: mul (no zero-init pass)
      float c0 = bflo(qv[0].x), c1 = bfhi(qv[0].x);
      float c2 = bflo(qv[0].y), c3 = bfhi(qv[0].y);
#pragma unroll
      for (int j = 0; j < 4; ++j) {
        float av = atf[0][j];
        a[0][j] = c0 * av;
        a[1][j] = c1 * av;
        a[2][j] = c2 * av;
        a[3][j] = c3 * av;
      }
    }
#pragma unroll
    for (int p = 1; p < 9; ++p) {
      float c0 = bflo(qv[p].x), c1 = bfhi(qv[p].x);
      float c2 = bflo(qv[p].y), c3 = bfhi(qv[p].y);
#pragma unroll
      for (int j = 0; j < 4; ++j) {
        float av = atf[p][j];
        a[0][j] = fmaf(c0, av, a[0][j]);
        a[1][j] = fmaf(c1, av, a[1][j]);
        a[2][j] = fmaf(c2, av, a[2][j]);
        a[3][j] = fmaf(c3, av, a[3][j]);
      }
    }
#pragma unroll
    for (int cc = 0; cc < 4; ++cc) {
      int g = (cc * 4 + fh4) ^ ((pxl_b & 7) << 1);
      uint2 val;
      val.x = cvtpk(a[cc][0], a[cc][1]);
      val.y = cvtpk(a[cc][2], a[cc][3]);
      *(uint2*)&Asw[pxl_b * 64 + g * 4] = val;
    }
  };

  qload(0);
  build();

  for (int rd = 0; rd < 16; ++rd) {
    // 1) issue ALL 16 B-frag loads via asm (un-sinkable).
    short8 Bf[2][2][4];
    {
      const unsigned short* b0 = coefswz + (size_t)rd * 8192 + lane * 8;
      const unsigned short* b1 = b0 + 2048;
      const unsigned short* b2 = b0 + 4096;
      const unsigned short* b3 = b0 + 6144;
      GLOAD(Bf[0][0][0], b0, "0");
      GLOAD(Bf[0][0][1], b0, "1024");
      GLOAD(Bf[0][0][2], b0, "2048");
      GLOAD(Bf[0][0][3], b0, "3072");
      GLOAD(Bf[0][1][0], b1, "0");
      GLOAD(Bf[0][1][1], b1, "1024");
      GLOAD(Bf[0][1][2], b1, "2048");
      GLOAD(Bf[0][1][3], b1, "3072");
      GLOAD(Bf[1][0][0], b2, "0");
      GLOAD(Bf[1][0][1], b2, "1024");
      GLOAD(Bf[1][0][2], b2, "2048");
      GLOAD(Bf[1][0][3], b2, "3072");
      GLOAD(Bf[1][1][0], b3, "0");
      GLOAD(Bf[1][1][1], b3, "1024");
      GLOAD(Bf[1][1][2], b3, "2048");
      GLOAD(Bf[1][1][3], b3, "3072");
    }
    // 2) A frags for rd (per-wave DS in-order -> WAR-safe single buffer)
    short8 Af[2];
#pragma unroll
    for (int kc = 0; kc < 2; ++kc) {
      int u16 = (kc * 4 + lq) ^ (lm & 7);
      Af[kc] = *(const short8*)&Asw[lm * 64 + u16 * 8];
    }
    __builtin_amdgcn_sched_barrier(0);
    // 3) next-chunk build: VALU blanket hiding the B-load latency
    if (rd < 15) {
      qload(rd + 1);
      build();
    }
    // 4) manual wait for the asm loads, fenced (rule #18), then consume.
    asm volatile("s_waitcnt vmcnt(0)" ::: "memory");
    __builtin_amdgcn_sched_barrier(0);
    __builtin_amdgcn_s_setprio(1);
#pragma unroll
    for (int kc = 0; kc < 2; ++kc)
#pragma unroll
      for (int wj = 0; wj < 2; ++wj)
#pragma unroll
        for (int u = 0; u < 4; ++u)
          acc[wj][u] = MFMA16(Af[kc], Bf[kc][wj][u], acc[wj][u]);
    __builtin_amdgcn_s_setprio(0);
  }

  // epilogue: direct float4 stores (C/D reg-run contiguous along p)
  float* outn = out + (size_t)n * 128 * 4096;
#pragma unroll
  for (int wj = 0; wj < 2; ++wj)
#pragma unroll
    for (int u = 0; u < 4; ++u) {
      int oc = wj * 64 + u * 16 + lm;
      int gpx = w * 16 + lq * 4;  // tile-local px of acc run
      int qx = gpx >> 3, py0 = gpx & 7;
      *(float4*)&outn[((size_t)oc * 64 + q0 + qx) * 64 + p0 + py0] =
          make_float4(acc[wj][u][0], acc[wj][u][1], acc[wj][u][2],
                      acc[wj][u][3]);
    }
}

// ---------------------------------------------------------------------------
extern "C" void kernel_launch(void* const* d_in, const int* in_sizes, int n_in,
                              void* d_out, int out_size, void* d_ws,
                              size_t ws_size, hipStream_t stream) {
  const float* x = (const float*)d_in[0];
  const float* conv1_w = (const float*)d_in[1];
  const float* conv1_b = (const float*)d_in[2];
  const float* bn1_g = (const float*)d_in[3];
  const float* bn1_b = (const float*)d_in[4];
  const float* bn1_m = (const float*)d_in[5];
  const float* bn1_v = (const float*)d_in[6];
  const float* conv2_w = (const float*)d_in[7];
  const float* conv2_b = (const float*)d_in[8];
  const float* bn2_g = (const float*)d_in[9];
  const float* bn2_b = (const float*)d_in[10];
  const float* bn2_m = (const float*)d_in[11];
  const float* bn2_v = (const float*)d_in[12];
  const float* bases = (const float*)d_in[13];
  const float* coef = (const float*)d_in[14];
  float* out = (float*)d_out;

  char* ws = (char*)d_ws;
  unsigned short* xbuf = (unsigned short*)(ws);             // 8,388,608 B
  unsigned short* w1swz = (unsigned short*)(ws + 20971520); // 73,728 B
  unsigned short* w2swz = (unsigned short*)(ws + 21045248); // 110,592 B
  unsigned short* coefswz = (unsigned short*)(ws + 21155840); // 262,144 B

  prep_all<<<dim3(96, NBATCH), 256, 0, stream>>>(x, xbuf, conv1_w, conv2_w,
                                                 coef, w1swz, w2swz, coefswz);
  mega<<<dim3(64, NBATCH), 256, 0, stream>>>(
      xbuf, w1swz, w2swz, conv1_b, bn1_g, bn1_b, bn1_m, bn1_v, conv2_b, bn2_g,
      bn2_b, bn2_m, bn2_v, bases, coefswz, out);
}